// Round 3
// baseline (5778.731 us; speedup 1.0000x reference)
//
#include <hip/hip_runtime.h>
#include <math.h>

#define N_NODES 100000
#define N_EDGES 1600000

static constexpr int GEMM_GRID = (N_NODES + 63) / 64;     // 1563
static constexpr int NODE_GRID = (N_NODES + 255) / 256;   // 391
static constexpr int DENSE_GRID = (N_NODES + 63) / 64;    // 1563
static constexpr unsigned M_INIT = 0x007FFFFFu;           // fmap(-inf)

__device__ __forceinline__ float lrelu(float v, float s){ return v >= 0.f ? v : v*s; }

__device__ __forceinline__ unsigned fmap(float v){
    unsigned u = __float_as_uint(v);
    return (u & 0x80000000u) ? ~u : (u | 0x80000000u);
}

// ---------------- generic row-block GEMM: C = act(A@B + bias) ----------------
// TIN:  A is [K, N_NODES] channel-major (transposed), else [N_NODES, K] stride K.
// TOUT: C written as [M, N_NODES] channel-major with col stride OS, else row-major stride OS.
// Block owns 64 rows and ALL M columns (M <= 64*NCT) -> in-place safe for row-major.
template<int NCT, bool TIN, bool TOUT>
__global__ __launch_bounds__(256) void gemm_rows(
    const float* A, const float* __restrict__ B, const float* __restrict__ bias,
    float* C, int K, int M, int OS, float slope)
{
    constexpr int BNtot = 64 * NCT;
    __shared__ float At[16 * 68];
    __shared__ float Bt[16 * BNtot];
    const int t  = threadIdx.x;
    const int r0 = blockIdx.x * 64;
    const int tx = t & 15, ty = t >> 4;

    float acc[4][4 * NCT];
#pragma unroll
    for (int i = 0; i < 4; i++)
#pragma unroll
        for (int j = 0; j < 4 * NCT; j++) acc[i][j] = 0.f;

    for (int k0 = 0; k0 < K; k0 += 16) {
        if (TIN) { // A channel-major: direct coalesced copy
            int kk = t >> 4, rq = t & 15;
            float4 v = make_float4(0.f, 0.f, 0.f, 0.f);
            if (k0 + kk < K)
                v = *(const float4*)(A + (long)(k0 + kk) * N_NODES + r0 + rq * 4);
            *(float4*)(At + kk * 68 + rq * 4) = v;
        } else {   // A row-major: transpose while staging
            int r = t >> 2, kq = t & 3;
            float4 v = make_float4(0.f, 0.f, 0.f, 0.f);
            int row = r0 + r, kk = k0 + kq * 4;
            if (row < N_NODES && kk < K)
                v = *(const float4*)(A + (long)row * K + kk);
            At[(kq*4+0)*68 + r] = v.x;
            At[(kq*4+1)*68 + r] = v.y;
            At[(kq*4+2)*68 + r] = v.z;
            At[(kq*4+3)*68 + r] = v.w;
        }
#pragma unroll
        for (int i = 0; i < NCT; i++) { // stage B
            int idx = i * 256 + t;
            constexpr int fpr = BNtot / 4;
            int kk = idx / fpr, mq = idx % fpr;
            float4 v = make_float4(0.f, 0.f, 0.f, 0.f);
            if (k0 + kk < K && mq * 4 < M)
                v = *(const float4*)(B + (long)(k0 + kk) * M + mq * 4);
            *(float4*)(Bt + kk * BNtot + mq * 4) = v;
        }
        __syncthreads();
#pragma unroll
        for (int kk = 0; kk < 16; kk++) {
            float4 av = *(const float4*)(At + kk * 68 + ty * 4);
            float a_[4] = {av.x, av.y, av.z, av.w};
#pragma unroll
            for (int ct = 0; ct < NCT; ct++) {
                float4 bv = *(const float4*)(Bt + kk * BNtot + ct * 64 + tx * 4);
                float b_[4] = {bv.x, bv.y, bv.z, bv.w};
#pragma unroll
                for (int i = 0; i < 4; i++)
#pragma unroll
                    for (int j = 0; j < 4; j++)
                        acc[i][ct*4+j] += a_[i] * b_[j];
            }
        }
        __syncthreads();
    }
#pragma unroll
    for (int i = 0; i < 4; i++) {
        int row = r0 + ty * 4 + i;
        if (row >= N_NODES) continue;
#pragma unroll
        for (int ct = 0; ct < NCT; ct++)
#pragma unroll
            for (int j = 0; j < 4; j++) {
                int col = ct * 64 + tx * 4 + j;
                if (col < M) {
                    float v = acc[i][ct*4+j];
                    if (bias) v += bias[col];
                    v = lrelu(v, slope);
                    if (TOUT) C[(long)col * OS + row] = v;
                    else      C[(long)row * OS + col] = v;
                }
            }
    }
}

// ---------------- BN stats over channel-major layout ----------------
// grid (C0, 4): block reduces one quarter of one channel's N values.
__global__ void bn_stats_t(const float* __restrict__ Xt,
                           float* __restrict__ gsum, float* __restrict__ gsq)
{
    int ch = blockIdx.x, part = blockIdx.y, t = threadIdx.x;
    const float* p = Xt + (long)ch * N_NODES;
    float s = 0.f, q = 0.f;
    for (long i = (long)part * 25000 + t * 4; i < (long)(part + 1) * 25000; i += 1024) {
        float4 v = *(const float4*)(p + i);
        s += v.x + v.y + v.z + v.w;
        q += v.x*v.x + v.y*v.y + v.z*v.z + v.w*v.w;
    }
#pragma unroll
    for (int m = 1; m < 64; m <<= 1) {
        s += __shfl_xor(s, m, 64);
        q += __shfl_xor(q, m, 64);
    }
    __shared__ float ls[4], lq[4];
    int wid = t >> 6;
    if ((t & 63) == 0) { ls[wid] = s; lq[wid] = q; }
    __syncthreads();
    if (t == 0) {
        atomicAdd(gsum + ch, ls[0] + ls[1] + ls[2] + ls[3]);
        atomicAdd(gsq  + ch, lq[0] + lq[1] + lq[2] + lq[3]);
    }
}

__global__ void bn_finalize(const float* __restrict__ gsum, const float* __restrict__ gsq,
                            const float* __restrict__ gamma, const float* __restrict__ beta,
                            float* __restrict__ Aab, float* __restrict__ Bab, int C)
{
    int c = threadIdx.x;
    if (c >= C) return;
    float mu  = gsum[c] * (1.f / N_NODES);
    float var = gsq[c]  * (1.f / N_NODES) - mu * mu;
    float A = rsqrtf(var + 1e-5f) * gamma[c];
    Aab[c] = A;
    Bab[c] = beta[c] - mu * A;
}

// ---------------- densenet layer, channel-major ----------------
__global__ __launch_bounds__(64) void dense_conv_t(
    float* __restrict__ Xt, int C,
    const float* __restrict__ W, int WS,
    const float* __restrict__ Aab, const float* __restrict__ Bab,
    float* __restrict__ gsum, float* __restrict__ gsq)
{
    __shared__ float w_lds[12 * 132];
    __shared__ float a_lds[132], b_lds[132];
    int t = threadIdx.x;
#pragma unroll
    for (int g = 0; g < 12; g++)
        for (int c = t; c < C; c += 64)
            w_lds[g * 132 + c] = W[g * WS + c];
    for (int c = t; c < C; c += 64) { a_lds[c] = Aab[c]; b_lds[c] = Bab[c]; }
    __syncthreads();

    long n = (long)blockIdx.x * 64 + t;
    bool valid = (n < N_NODES);
    long nn = valid ? n : (N_NODES - 1);
    const float* xp = Xt + nn;
    float acc[12];
#pragma unroll
    for (int g = 0; g < 12; g++) acc[g] = 0.f;

    for (int c0 = 0; c0 < C; c0 += 12) {
        float v[12];
#pragma unroll
        for (int j = 0; j < 12; j++)
            v[j] = xp[(long)(c0 + j) * N_NODES];
#pragma unroll
        for (int j = 0; j < 12; j++) {
            int ch = c0 + j;
            float u = a_lds[ch] * v[j] + b_lds[ch];
            u = (u >= 0.f) ? u : 0.01f * u;
#pragma unroll
            for (int g = 0; g < 12; g++)
                acc[g] += u * w_lds[g * 132 + ch];
        }
    }
    if (valid) {
#pragma unroll
        for (int g = 0; g < 12; g++)
            Xt[(long)(C + g) * N_NODES + n] = acc[g];
    }
    // fused stats for the 12 new channels
    float sv[12], qv[12];
#pragma unroll
    for (int g = 0; g < 12; g++) { float v2 = valid ? acc[g] : 0.f; sv[g] = v2; qv[g] = v2 * v2; }
#pragma unroll
    for (int m = 1; m < 64; m <<= 1)
#pragma unroll
        for (int g = 0; g < 12; g++) {
            sv[g] += __shfl_xor(sv[g], m, 64);
            qv[g] += __shfl_xor(qv[g], m, 64);
        }
    if (t == 0)
#pragma unroll
        for (int g = 0; g < 12; g++) {
            atomicAdd(gsum + C + g, sv[g]);
            atomicAdd(gsq  + C + g, qv[g]);
        }
}

// ---------------- GAT ----------------
__global__ void gat_scores(const float* __restrict__ H, int F, const float* __restrict__ a,
                           float* __restrict__ sd, float* __restrict__ ss)
{
    long n = (long)blockIdx.x * 256 + threadIdx.x;
    if (n >= N_NODES) return;
    const float* h = H + n * F;
    float s1 = 0.f, s2 = 0.f;
    for (int f = 0; f < F; f += 4) {
        float4 hv = *(const float4*)(h + f);
        s1 += hv.x*a[f] + hv.y*a[f+1] + hv.z*a[f+2] + hv.w*a[f+3];
        s2 += hv.x*a[F+f] + hv.y*a[F+f+1] + hv.z*a[F+f+2] + hv.w*a[F+f+3];
    }
    sd[n] = s1; ss[n] = s2;
}

__global__ void gat_init(unsigned* __restrict__ m_u, float* __restrict__ den)
{
    long n = (long)blockIdx.x * 256 + threadIdx.x;
    if (n >= N_NODES) return;
    m_u[n] = M_INIT;
    den[n] = 0.f;
}

__global__ void gat_edge1(const int* __restrict__ src, const int* __restrict__ dst,
                          const float* __restrict__ sd, const float* __restrict__ ss,
                          unsigned* __restrict__ m_u)
{
    for (long e = (long)blockIdx.x * 256 + threadIdx.x; e < N_EDGES; e += (long)gridDim.x * 256) {
        int d = dst[e], s = src[e];
        float v = sd[d] + ss[s];
        v = (v >= 0.f) ? v : 0.2f * v;
        atomicMax(m_u + d, fmap(v));
    }
}

__global__ void gat_fixm(unsigned* __restrict__ m_u)
{
    long n = (long)blockIdx.x * 256 + threadIdx.x;
    if (n >= N_NODES) return;
    unsigned u = m_u[n];
    float m;
    if (u == M_INIT) m = 0.f;   // empty segment: where(isfinite(m), m, 0)
    else m = (u & 0x80000000u) ? __uint_as_float(u ^ 0x80000000u) : __uint_as_float(~u);
    m_u[n] = __float_as_uint(m);
}

__global__ void gat_edge2(const int* __restrict__ src, const int* __restrict__ dst,
                          const float* __restrict__ sd, const float* __restrict__ ss,
                          const float* __restrict__ mf, float* __restrict__ exv,
                          float* __restrict__ den)
{
    for (long e = (long)blockIdx.x * 256 + threadIdx.x; e < N_EDGES; e += (long)gridDim.x * 256) {
        int d = dst[e], s = src[e];
        float v = sd[d] + ss[s];
        v = (v >= 0.f) ? v : 0.2f * v;
        float x = __expf(v - mf[d]);
        exv[e] = x;
        atomicAdd(den + d, x);
    }
}

// wave per node: outT[ch][n] = sum_e alpha_e * H[src_e][ch] + bias[ch]  (transposed write)
__global__ __launch_bounds__(256) void gat_aggregate(
    const int* __restrict__ src, const float* __restrict__ exv,
    const float* __restrict__ den, const int* __restrict__ rstart,
    const int* __restrict__ csr, const float* __restrict__ H, int F,
    const float* __restrict__ bias, float* __restrict__ outT)
{
    int wid  = threadIdx.x >> 6;
    int lane = threadIdx.x & 63;
    long node = (long)blockIdx.x * 4 + wid;
    if (node >= N_NODES) return;
    int st = rstart[node], en = rstart[node + 1];
    float invden = 1.f / (den[node] + 1e-16f);
    float acc = 0.f;
    for (int base = st; base < en; base += 64) {
        int cnt = min(64, en - base);
        float al = 0.f; int sj = 0;
        if (lane < cnt) {
            int eid = csr[base + lane];
            al = exv[eid] * invden;
            sj = src[eid];
        }
        for (int j = 0; j < cnt; j++) {
            float a = __shfl(al, j, 64);
            int   s = __shfl(sj, j, 64);
            if (lane < F) acc += a * H[(long)s * F + lane];
        }
    }
    if (lane < F) outT[(long)lane * N_NODES + node] = acc + bias[lane];
}

// ---------------- final transpose [132][N] -> [N,132] ----------------
__global__ __launch_bounds__(256) void transpose_out(const float* __restrict__ Xt,
                                                     float* __restrict__ out)
{
    __shared__ float tile[64 * 133];
    int t = threadIdx.x;
    long n0 = (long)blockIdx.x * 64;
    int lane = t & 63, cq = t >> 6;
    for (int c = cq; c < 132; c += 4) {
        long n = n0 + lane;
        float v = (n < N_NODES) ? Xt[(long)c * N_NODES + n] : 0.f;
        tile[lane * 133 + c] = v;
    }
    __syncthreads();
    for (int idx = t; idx < 64 * 132; idx += 256) {
        int r = idx / 132, c = idx % 132;
        long n = n0 + r;
        if (n < N_NODES) out[n * 132 + c] = tile[r * 133 + c];
    }
}

// ---------------- CSR build ----------------
__global__ void hist_kernel(const int* __restrict__ dst, int* __restrict__ deg)
{
    for (long e = (long)blockIdx.x * 256 + threadIdx.x; e < N_EDGES; e += (long)gridDim.x * 256)
        atomicAdd(deg + dst[e], 1);
}

__global__ void scan1(const int* __restrict__ deg, int* __restrict__ rtmp, int* __restrict__ parts)
{
    __shared__ int ls[256];
    int t = threadIdx.x;
    long i = (long)blockIdx.x * 256 + t;
    int v = (i < N_NODES) ? deg[i] : 0;
    ls[t] = v; __syncthreads();
    for (int o = 1; o < 256; o <<= 1) {
        int y = (t >= o) ? ls[t - o] : 0;
        __syncthreads();
        ls[t] += y;
        __syncthreads();
    }
    if (i < N_NODES) rtmp[i] = ls[t] - v;
    if (t == 255) parts[blockIdx.x] = ls[255];
}

__global__ void scan2(int* __restrict__ parts, int nb, int* __restrict__ total_out)
{
    __shared__ int ls[512];
    int t = threadIdx.x;
    int v = (t < nb) ? parts[t] : 0;
    ls[t] = v; __syncthreads();
    for (int o = 1; o < 512; o <<= 1) {
        int y = (t >= o) ? ls[t - o] : 0;
        __syncthreads();
        ls[t] += y;
        __syncthreads();
    }
    if (t < nb) parts[t] = ls[t] - v;
    if (t == 0) total_out[0] = ls[511];
}

__global__ void scan3(const int* __restrict__ rtmp, const int* __restrict__ parts,
                      int* __restrict__ rstart, int* __restrict__ cursor)
{
    long i = (long)blockIdx.x * 256 + threadIdx.x;
    if (i < N_NODES) {
        int v = rtmp[i] + parts[i >> 8];
        rstart[i] = v;
        cursor[i] = v;
    }
}

__global__ void scatter_k(const int* __restrict__ dst, int* __restrict__ cursor,
                          int* __restrict__ csr)
{
    for (long e = (long)blockIdx.x * 256 + threadIdx.x; e < N_EDGES; e += (long)gridDim.x * 256) {
        int pos = atomicAdd(cursor + dst[e], 1);
        csr[pos] = (int)e;
    }
}

// ---------------- host helpers ----------------
static void run_dense_block_t(hipStream_t stream, float* Xt, int C0,
                              const float* convW, int WS,
                              const float* gamma, const float* beta,
                              float* gsum, float* gsq, float* Aab, float* Bab)
{
    hipMemsetAsync(gsum, 0, 264 * sizeof(float), stream);  // gsum[132] + gsq[132]
    bn_stats_t<<<dim3(C0, 4), 256, 0, stream>>>(Xt, gsum, gsq);
    for (int i = 0; i < 6; i++) {
        int C = C0 + 12 * i;
        bn_finalize<<<1, 256, 0, stream>>>(gsum, gsq, gamma + i * WS, beta + i * WS, Aab, Bab, C);
        dense_conv_t<<<DENSE_GRID, 64, 0, stream>>>(Xt, C, convW + (size_t)i * 12 * WS, WS,
                                                    Aab, Bab, gsum, gsq);
    }
}

static void run_gat(hipStream_t stream, const float* XtIn, int K,
                    const float* W, const float* a, const float* bias, int F,
                    float* hbuf, float* outT,
                    const int* src, const int* dst,
                    float* sd, float* ss, unsigned* m_u, float* den,
                    float* exv, const int* rstart, const int* csr)
{
    gemm_rows<1, true, false><<<GEMM_GRID, 256, 0, stream>>>(XtIn, W, nullptr, hbuf, K, F, F, 1.0f);
    gat_scores<<<NODE_GRID, 256, 0, stream>>>(hbuf, F, a, sd, ss);
    gat_init<<<NODE_GRID, 256, 0, stream>>>(m_u, den);
    gat_edge1<<<2048, 256, 0, stream>>>(src, dst, sd, ss, m_u);
    gat_fixm<<<NODE_GRID, 256, 0, stream>>>(m_u);
    gat_edge2<<<2048, 256, 0, stream>>>(src, dst, sd, ss, (const float*)m_u, exv, den);
    gat_aggregate<<<(N_NODES + 3) / 4, 256, 0, stream>>>(src, exv, den, rstart, csr,
                                                         hbuf, F, bias, outT);
}

extern "C" void kernel_launch(void* const* d_in, const int* in_sizes, int n_in,
                              void* d_out, int out_size, void* d_ws, size_t ws_size,
                              hipStream_t stream)
{
    const float* x     = (const float*)d_in[0];
    const int*   src   = (const int*)d_in[1];
    const int*   dst   = (const int*)d_in[2];
    const float* w1    = (const float*)d_in[3];
    const float* b1    = (const float*)d_in[4];
    const float* w2    = (const float*)d_in[5];
    const float* b2    = (const float*)d_in[6];
    const float* w3    = (const float*)d_in[7];
    const float* b3    = (const float*)d_in[8];
    const float* conv1 = (const float*)d_in[9];
    const float* bn1g  = (const float*)d_in[10];
    const float* bn1b  = (const float*)d_in[11];
    const float* g1w   = (const float*)d_in[12];
    const float* g1a   = (const float*)d_in[13];
    const float* g1b   = (const float*)d_in[14];
    const float* conv2 = (const float*)d_in[15];
    const float* bn2g  = (const float*)d_in[16];
    const float* bn2b  = (const float*)d_in[17];
    const float* g2w   = (const float*)d_in[18];
    const float* g2a   = (const float*)d_in[19];
    const float* g2b   = (const float*)d_in[20];
    const float* conv3 = (const float*)d_in[21];
    const float* bn3g  = (const float*)d_in[22];
    const float* bn3b  = (const float*)d_in[23];
    float* out = (float*)d_out;

    char* ws = (char*)d_ws;
    size_t off = 0;
    auto alloc = [&](size_t bytes) -> void* {
        void* p = ws + off;
        off += (bytes + 255) & ~(size_t)255;
        return p;
    };
    float*    h      = (float*)alloc((size_t)N_NODES * 256 * 4); // MLP; later gat1h/gat2h + Xt3
    float*    Xt1    = (float*)alloc((size_t)96  * N_NODES * 4); // dense block 1 (transposed)
    float*    Xt2    = (float*)alloc((size_t)120 * N_NODES * 4); // dense block 2 (transposed)
    float*    exv    = (float*)alloc((size_t)N_EDGES * 4);
    int*      csr    = (int*)alloc((size_t)N_EDGES * 4);
    int*      deg    = (int*)alloc((size_t)N_NODES * 4);
    int*      rtmp   = (int*)alloc((size_t)N_NODES * 4);
    int*      rstart = (int*)alloc((size_t)(N_NODES + 1) * 4);
    int*      cursor = (int*)alloc((size_t)N_NODES * 4);
    int*      parts  = (int*)alloc(2048);
    unsigned* m_u    = (unsigned*)alloc((size_t)N_NODES * 4);
    float*    den    = (float*)alloc((size_t)N_NODES * 4);
    float*    sd     = (float*)alloc((size_t)N_NODES * 4);
    float*    ss     = (float*)alloc((size_t)N_NODES * 4);
    float*    gsum   = (float*)alloc(264 * 4);
    float*    gsq    = gsum + 132;
    float*    Aab    = (float*)alloc(132 * 4);
    float*    Bab    = (float*)alloc(132 * 4);

    float* gat1h = h;                                   // [N,48] = 19.2 MB (h free after MLP)
    float* gat2h = h;                                   // [N,60] = 24 MB
    float* Xt3   = (float*)((char*)h + 33554432);       // [132][N] = 52.8 MB at h+32MB (fits in 102.4)

    // ---- CSR by dst (shared by both GATs) ----
    hipMemsetAsync(deg, 0, (size_t)N_NODES * 4, stream);
    hist_kernel<<<2048, 256, 0, stream>>>(dst, deg);
    scan1<<<NODE_GRID, 256, 0, stream>>>(deg, rtmp, parts);
    scan2<<<1, 512, 0, stream>>>(parts, NODE_GRID, rstart + N_NODES);
    scan3<<<NODE_GRID, 256, 0, stream>>>(rtmp, parts, rstart, cursor);
    scatter_k<<<2048, 256, 0, stream>>>(dst, cursor, csr);

    // ---- MLP ----
    gemm_rows<4, false, false><<<GEMM_GRID, 256, 0, stream>>>(x, w1, b1, h,   64,  256, 256, 0.01f);
    gemm_rows<4, false, false><<<GEMM_GRID, 256, 0, stream>>>(h, w2, b2, h,   256, 256, 256, 0.01f);
    gemm_rows<1, false, true ><<<GEMM_GRID, 256, 0, stream>>>(h, w3, b3, Xt1, 256, 24, N_NODES, 0.01f);

    // ---- dense block 1 (24 -> 96, channel-major) ----
    run_dense_block_t(stream, Xt1, 24, conv1, 84, bn1g, bn1b, gsum, gsq, Aab, Bab);

    // ---- GAT 1 (96 -> 48), output transposed into Xt2 rows 0..47 ----
    run_gat(stream, Xt1, 96, g1w, g1a, g1b, 48, gat1h, Xt2,
            src, dst, sd, ss, m_u, den, exv, rstart, csr);

    // ---- dense block 2 (48 -> 120) ----
    run_dense_block_t(stream, Xt2, 48, conv2, 108, bn2g, bn2b, gsum, gsq, Aab, Bab);

    // ---- GAT 2 (120 -> 60), output transposed into Xt3 rows 0..59 ----
    run_gat(stream, Xt2, 120, g2w, g2a, g2b, 60, gat2h, Xt3,
            src, dst, sd, ss, m_u, den, exv, rstart, csr);

    // ---- dense block 3 (60 -> 132) ----
    run_dense_block_t(stream, Xt3, 60, conv3, 120, bn3g, bn3b, gsum, gsq, Aab, Bab);

    // ---- final transpose to row-major d_out ----
    transpose_out<<<GEMM_GRID, 256, 0, stream>>>(Xt3, out);
}

// Round 4
// 1831.645 us; speedup vs baseline: 3.1549x; 3.1549x over previous
//
#include <hip/hip_runtime.h>
#include <math.h>

#define N_NODES 100000
#define N_EDGES 1600000

static constexpr int GEMM_GRID = (N_NODES + 63) / 64;     // 1563
static constexpr int NODE_GRID = (N_NODES + 255) / 256;   // 391
static constexpr int DENSE_GRID = (N_NODES + 63) / 64;    // 1563
static constexpr unsigned M_INIT = 0x007FFFFFu;           // fmap(-inf)

__device__ __forceinline__ float lrelu(float v, float s){ return v >= 0.f ? v : v*s; }

__device__ __forceinline__ unsigned fmap(float v){
    unsigned u = __float_as_uint(v);
    return (u & 0x80000000u) ? ~u : (u | 0x80000000u);
}

// ---------------- generic row-block GEMM: C = act(A@B + bias) ----------------
// TIN:  A is [K, N_NODES] channel-major (transposed), else [N_NODES, K] stride K.
// TOUT: C written as [M, N_NODES] channel-major with col stride OS, else row-major stride OS.
// Block owns 64 rows and ALL M columns (M <= 64*NCT) -> in-place safe for row-major.
template<int NCT, bool TIN, bool TOUT>
__global__ __launch_bounds__(256) void gemm_rows(
    const float* A, const float* __restrict__ B, const float* __restrict__ bias,
    float* C, int K, int M, int OS, float slope)
{
    constexpr int BNtot = 64 * NCT;
    __shared__ float At[16 * 68];
    __shared__ float Bt[16 * BNtot];
    const int t  = threadIdx.x;
    const int r0 = blockIdx.x * 64;
    const int tx = t & 15, ty = t >> 4;

    float acc[4][4 * NCT];
#pragma unroll
    for (int i = 0; i < 4; i++)
#pragma unroll
        for (int j = 0; j < 4 * NCT; j++) acc[i][j] = 0.f;

    for (int k0 = 0; k0 < K; k0 += 16) {
        if (TIN) { // A channel-major: direct coalesced copy
            int kk = t >> 4, rq = t & 15;
            float4 v = make_float4(0.f, 0.f, 0.f, 0.f);
            if (k0 + kk < K)
                v = *(const float4*)(A + (long)(k0 + kk) * N_NODES + r0 + rq * 4);
            *(float4*)(At + kk * 68 + rq * 4) = v;
        } else {   // A row-major: transpose while staging
            int r = t >> 2, kq = t & 3;
            float4 v = make_float4(0.f, 0.f, 0.f, 0.f);
            int row = r0 + r, kk = k0 + kq * 4;
            if (row < N_NODES && kk < K)
                v = *(const float4*)(A + (long)row * K + kk);
            At[(kq*4+0)*68 + r] = v.x;
            At[(kq*4+1)*68 + r] = v.y;
            At[(kq*4+2)*68 + r] = v.z;
            At[(kq*4+3)*68 + r] = v.w;
        }
#pragma unroll
        for (int i = 0; i < NCT; i++) { // stage B
            int idx = i * 256 + t;
            constexpr int fpr = BNtot / 4;
            int kk = idx / fpr, mq = idx % fpr;
            float4 v = make_float4(0.f, 0.f, 0.f, 0.f);
            if (k0 + kk < K && mq * 4 < M)
                v = *(const float4*)(B + (long)(k0 + kk) * M + mq * 4);
            *(float4*)(Bt + kk * BNtot + mq * 4) = v;
        }
        __syncthreads();
#pragma unroll
        for (int kk = 0; kk < 16; kk++) {
            float4 av = *(const float4*)(At + kk * 68 + ty * 4);
            float a_[4] = {av.x, av.y, av.z, av.w};
#pragma unroll
            for (int ct = 0; ct < NCT; ct++) {
                float4 bv = *(const float4*)(Bt + kk * BNtot + ct * 64 + tx * 4);
                float b_[4] = {bv.x, bv.y, bv.z, bv.w};
#pragma unroll
                for (int i = 0; i < 4; i++)
#pragma unroll
                    for (int j = 0; j < 4; j++)
                        acc[i][ct*4+j] += a_[i] * b_[j];
            }
        }
        __syncthreads();
    }
#pragma unroll
    for (int i = 0; i < 4; i++) {
        int row = r0 + ty * 4 + i;
        if (row >= N_NODES) continue;
#pragma unroll
        for (int ct = 0; ct < NCT; ct++)
#pragma unroll
            for (int j = 0; j < 4; j++) {
                int col = ct * 64 + tx * 4 + j;
                if (col < M) {
                    float v = acc[i][ct*4+j];
                    if (bias) v += bias[col];
                    v = lrelu(v, slope);
                    if (TOUT) C[(long)col * OS + row] = v;
                    else      C[(long)row * OS + col] = v;
                }
            }
    }
}

// ---------------- BN stats over channel-major layout ----------------
// grid (C0, 4): block reduces one quarter of one channel's N values.
// Atomic contention fine here: only 4 atomics per channel.
__global__ void bn_stats_t(const float* __restrict__ Xt,
                           float* __restrict__ gsum, float* __restrict__ gsq)
{
    int ch = blockIdx.x, part = blockIdx.y, t = threadIdx.x;
    const float* p = Xt + (long)ch * N_NODES;
    float s = 0.f, q = 0.f;
    for (long i = (long)part * 25000 + t * 4; i < (long)(part + 1) * 25000; i += 1024) {
        float4 v = *(const float4*)(p + i);
        s += v.x + v.y + v.z + v.w;
        q += v.x*v.x + v.y*v.y + v.z*v.z + v.w*v.w;
    }
#pragma unroll
    for (int m = 1; m < 64; m <<= 1) {
        s += __shfl_xor(s, m, 64);
        q += __shfl_xor(q, m, 64);
    }
    __shared__ float ls[4], lq[4];
    int wid = t >> 6;
    if ((t & 63) == 0) { ls[wid] = s; lq[wid] = q; }
    __syncthreads();
    if (t == 0) {
        atomicAdd(gsum + ch, ls[0] + ls[1] + ls[2] + ls[3]);
        atomicAdd(gsq  + ch, lq[0] + lq[1] + lq[2] + lq[3]);
    }
}

// ---------------- reduce per-block partial stats -> gsum/gsq for 12 new channels -------
__global__ __launch_bounds__(256) void bn_reduce(
    const float* __restrict__ ps, const float* __restrict__ pq,
    float* __restrict__ gsum, float* __restrict__ gsq, int C)
{
    int g = blockIdx.x;       // 0..11
    int t = threadIdx.x;
    float s = 0.f, q = 0.f;
    for (int b = t; b < DENSE_GRID; b += 256) {
        s += ps[g * DENSE_GRID + b];
        q += pq[g * DENSE_GRID + b];
    }
    __shared__ float ls[256], lq[256];
    ls[t] = s; lq[t] = q; __syncthreads();
    for (int o = 128; o > 0; o >>= 1) {
        if (t < o) { ls[t] += ls[t + o]; lq[t] += lq[t + o]; }
        __syncthreads();
    }
    if (t == 0) { gsum[C + g] = ls[0]; gsq[C + g] = lq[0]; }
}

// ---------------- densenet layer, channel-major, no hot atomics ----------------
// Computes per-layer BN coeffs inline from persistent gsum/gsq + this layer's gamma/beta.
// Writes per-block partial stats of the 12 new channels to ps/pq (plain stores).
__global__ __launch_bounds__(64) void dense_conv_t(
    float* __restrict__ Xt, int C,
    const float* __restrict__ W, int WS,
    const float* __restrict__ gamma, const float* __restrict__ beta,
    const float* __restrict__ gsum, const float* __restrict__ gsq,
    float* __restrict__ ps, float* __restrict__ pq)
{
    __shared__ float w_lds[12 * 132];
    __shared__ float a_lds[132], b_lds[132];
    int t = threadIdx.x;
    for (int c = t; c < C; c += 64) {
        float mu  = gsum[c] * (1.f / N_NODES);
        float var = gsq[c]  * (1.f / N_NODES) - mu * mu;
        float A = rsqrtf(var + 1e-5f) * gamma[c];
        a_lds[c] = A;
        b_lds[c] = beta[c] - mu * A;
    }
#pragma unroll
    for (int g = 0; g < 12; g++)
        for (int c = t; c < C; c += 64)
            w_lds[g * 132 + c] = W[g * WS + c];
    __syncthreads();

    long n = (long)blockIdx.x * 64 + t;
    bool valid = (n < N_NODES);
    long nn = valid ? n : (N_NODES - 1);
    const float* xp = Xt + nn;
    float acc[12];
#pragma unroll
    for (int g = 0; g < 12; g++) acc[g] = 0.f;

    // software-pipelined channel loop: prefetch next 12 while computing current 12
    float v[12], vn[12];
#pragma unroll
    for (int j = 0; j < 12; j++) v[j] = xp[(long)j * N_NODES];
    for (int c0 = 0; c0 < C; c0 += 12) {
        if (c0 + 12 < C) {
#pragma unroll
            for (int j = 0; j < 12; j++)
                vn[j] = xp[(long)(c0 + 12 + j) * N_NODES];
        }
#pragma unroll
        for (int j = 0; j < 12; j++) {
            int ch = c0 + j;
            float u = a_lds[ch] * v[j] + b_lds[ch];
            u = (u >= 0.f) ? u : 0.01f * u;
#pragma unroll
            for (int g = 0; g < 12; g++)
                acc[g] += u * w_lds[g * 132 + ch];
        }
#pragma unroll
        for (int j = 0; j < 12; j++) v[j] = vn[j];
    }
    if (valid) {
#pragma unroll
        for (int g = 0; g < 12; g++)
            Xt[(long)(C + g) * N_NODES + n] = acc[g];
    }
    // wave-level partial stats for the 12 new channels -> per-block slots (no atomics)
    float sv[12], qv[12];
#pragma unroll
    for (int g = 0; g < 12; g++) { float v2 = valid ? acc[g] : 0.f; sv[g] = v2; qv[g] = v2 * v2; }
#pragma unroll
    for (int m = 1; m < 64; m <<= 1)
#pragma unroll
        for (int g = 0; g < 12; g++) {
            sv[g] += __shfl_xor(sv[g], m, 64);
            qv[g] += __shfl_xor(qv[g], m, 64);
        }
    if (t == 0) {
        int b = blockIdx.x;
#pragma unroll
        for (int g = 0; g < 12; g++) {
            ps[g * DENSE_GRID + b] = sv[g];
            pq[g * DENSE_GRID + b] = qv[g];
        }
    }
}

// ---------------- GAT ----------------
__global__ void gat_scores(const float* __restrict__ H, int F, const float* __restrict__ a,
                           float* __restrict__ sd, float* __restrict__ ss)
{
    long n = (long)blockIdx.x * 256 + threadIdx.x;
    if (n >= N_NODES) return;
    const float* h = H + n * F;
    float s1 = 0.f, s2 = 0.f;
    for (int f = 0; f < F; f += 4) {
        float4 hv = *(const float4*)(h + f);
        s1 += hv.x*a[f] + hv.y*a[f+1] + hv.z*a[f+2] + hv.w*a[f+3];
        s2 += hv.x*a[F+f] + hv.y*a[F+f+1] + hv.z*a[F+f+2] + hv.w*a[F+f+3];
    }
    sd[n] = s1; ss[n] = s2;
}

__global__ void gat_init(unsigned* __restrict__ m_u, float* __restrict__ den)
{
    long n = (long)blockIdx.x * 256 + threadIdx.x;
    if (n >= N_NODES) return;
    m_u[n] = M_INIT;
    den[n] = 0.f;
}

__global__ void gat_edge1(const int* __restrict__ src, const int* __restrict__ dst,
                          const float* __restrict__ sd, const float* __restrict__ ss,
                          unsigned* __restrict__ m_u)
{
    for (long e = (long)blockIdx.x * 256 + threadIdx.x; e < N_EDGES; e += (long)gridDim.x * 256) {
        int d = dst[e], s = src[e];
        float v = sd[d] + ss[s];
        v = (v >= 0.f) ? v : 0.2f * v;
        atomicMax(m_u + d, fmap(v));
    }
}

__global__ void gat_fixm(unsigned* __restrict__ m_u)
{
    long n = (long)blockIdx.x * 256 + threadIdx.x;
    if (n >= N_NODES) return;
    unsigned u = m_u[n];
    float m;
    if (u == M_INIT) m = 0.f;   // empty segment: where(isfinite(m), m, 0)
    else m = (u & 0x80000000u) ? __uint_as_float(u ^ 0x80000000u) : __uint_as_float(~u);
    m_u[n] = __float_as_uint(m);
}

__global__ void gat_edge2(const int* __restrict__ src, const int* __restrict__ dst,
                          const float* __restrict__ sd, const float* __restrict__ ss,
                          const float* __restrict__ mf, float* __restrict__ exv,
                          float* __restrict__ den)
{
    for (long e = (long)blockIdx.x * 256 + threadIdx.x; e < N_EDGES; e += (long)gridDim.x * 256) {
        int d = dst[e], s = src[e];
        float v = sd[d] + ss[s];
        v = (v >= 0.f) ? v : 0.2f * v;
        float x = __expf(v - mf[d]);
        exv[e] = x;
        atomicAdd(den + d, x);
    }
}

// wave per node: outT[ch][n] = sum_e alpha_e * H[src_e][ch] + bias[ch]  (transposed write)
__global__ __launch_bounds__(256) void gat_aggregate(
    const int* __restrict__ src, const float* __restrict__ exv,
    const float* __restrict__ den, const int* __restrict__ rstart,
    const int* __restrict__ csr, const float* __restrict__ H, int F,
    const float* __restrict__ bias, float* __restrict__ outT)
{
    int wid  = threadIdx.x >> 6;
    int lane = threadIdx.x & 63;
    long node = (long)blockIdx.x * 4 + wid;
    if (node >= N_NODES) return;
    int st = rstart[node], en = rstart[node + 1];
    float invden = 1.f / (den[node] + 1e-16f);
    float acc = 0.f;
    for (int base = st; base < en; base += 64) {
        int cnt = min(64, en - base);
        float al = 0.f; int sj = 0;
        if (lane < cnt) {
            int eid = csr[base + lane];
            al = exv[eid] * invden;
            sj = src[eid];
        }
        for (int j = 0; j < cnt; j++) {
            float a = __shfl(al, j, 64);
            int   s = __shfl(sj, j, 64);
            if (lane < F) acc += a * H[(long)s * F + lane];
        }
    }
    if (lane < F) outT[(long)lane * N_NODES + node] = acc + bias[lane];
}

// ---------------- final transpose [132][N] -> [N,132] ----------------
__global__ __launch_bounds__(256) void transpose_out(const float* __restrict__ Xt,
                                                     float* __restrict__ out)
{
    __shared__ float tile[64 * 133];
    int t = threadIdx.x;
    long n0 = (long)blockIdx.x * 64;
    int lane = t & 63, cq = t >> 6;
    for (int c = cq; c < 132; c += 4) {
        long n = n0 + lane;
        float v = (n < N_NODES) ? Xt[(long)c * N_NODES + n] : 0.f;
        tile[lane * 133 + c] = v;
    }
    __syncthreads();
    for (int idx = t; idx < 64 * 132; idx += 256) {
        int r = idx / 132, c = idx % 132;
        long n = n0 + r;
        if (n < N_NODES) out[n * 132 + c] = tile[r * 133 + c];
    }
}

// ---------------- CSR build ----------------
__global__ void hist_kernel(const int* __restrict__ dst, int* __restrict__ deg)
{
    for (long e = (long)blockIdx.x * 256 + threadIdx.x; e < N_EDGES; e += (long)gridDim.x * 256)
        atomicAdd(deg + dst[e], 1);
}

__global__ void scan1(const int* __restrict__ deg, int* __restrict__ rtmp, int* __restrict__ parts)
{
    __shared__ int ls[256];
    int t = threadIdx.x;
    long i = (long)blockIdx.x * 256 + t;
    int v = (i < N_NODES) ? deg[i] : 0;
    ls[t] = v; __syncthreads();
    for (int o = 1; o < 256; o <<= 1) {
        int y = (t >= o) ? ls[t - o] : 0;
        __syncthreads();
        ls[t] += y;
        __syncthreads();
    }
    if (i < N_NODES) rtmp[i] = ls[t] - v;
    if (t == 255) parts[blockIdx.x] = ls[255];
}

__global__ void scan2(int* __restrict__ parts, int nb, int* __restrict__ total_out)
{
    __shared__ int ls[512];
    int t = threadIdx.x;
    int v = (t < nb) ? parts[t] : 0;
    ls[t] = v; __syncthreads();
    for (int o = 1; o < 512; o <<= 1) {
        int y = (t >= o) ? ls[t - o] : 0;
        __syncthreads();
        ls[t] += y;
        __syncthreads();
    }
    if (t < nb) parts[t] = ls[t] - v;
    if (t == 0) total_out[0] = ls[511];
}

__global__ void scan3(const int* __restrict__ rtmp, const int* __restrict__ parts,
                      int* __restrict__ rstart, int* __restrict__ cursor)
{
    long i = (long)blockIdx.x * 256 + threadIdx.x;
    if (i < N_NODES) {
        int v = rtmp[i] + parts[i >> 8];
        rstart[i] = v;
        cursor[i] = v;
    }
}

__global__ void scatter_k(const int* __restrict__ dst, int* __restrict__ cursor,
                          int* __restrict__ csr)
{
    for (long e = (long)blockIdx.x * 256 + threadIdx.x; e < N_EDGES; e += (long)gridDim.x * 256) {
        int pos = atomicAdd(cursor + dst[e], 1);
        csr[pos] = (int)e;
    }
}

// ---------------- host helpers ----------------
static void run_dense_block_t(hipStream_t stream, float* Xt, int C0,
                              const float* convW, int WS,
                              const float* gamma, const float* beta,
                              float* gsum, float* gsq, float* ps, float* pq)
{
    hipMemsetAsync(gsum, 0, 264 * sizeof(float), stream);  // gsum[132] + gsq[132]
    bn_stats_t<<<dim3(C0, 4), 256, 0, stream>>>(Xt, gsum, gsq);
    for (int i = 0; i < 6; i++) {
        int C = C0 + 12 * i;
        dense_conv_t<<<DENSE_GRID, 64, 0, stream>>>(Xt, C, convW + (size_t)i * 12 * WS, WS,
                                                    gamma + (size_t)i * WS, beta + (size_t)i * WS,
                                                    gsum, gsq, ps, pq);
        if (i < 5)
            bn_reduce<<<12, 256, 0, stream>>>(ps, pq, gsum, gsq, C);
    }
}

static void run_gat(hipStream_t stream, const float* XtIn, int K,
                    const float* W, const float* a, const float* bias, int F,
                    float* hbuf, float* outT,
                    const int* src, const int* dst,
                    float* sd, float* ss, unsigned* m_u, float* den,
                    float* exv, const int* rstart, const int* csr)
{
    gemm_rows<1, true, false><<<GEMM_GRID, 256, 0, stream>>>(XtIn, W, nullptr, hbuf, K, F, F, 1.0f);
    gat_scores<<<NODE_GRID, 256, 0, stream>>>(hbuf, F, a, sd, ss);
    gat_init<<<NODE_GRID, 256, 0, stream>>>(m_u, den);
    gat_edge1<<<2048, 256, 0, stream>>>(src, dst, sd, ss, m_u);
    gat_fixm<<<NODE_GRID, 256, 0, stream>>>(m_u);
    gat_edge2<<<2048, 256, 0, stream>>>(src, dst, sd, ss, (const float*)m_u, exv, den);
    gat_aggregate<<<(N_NODES + 3) / 4, 256, 0, stream>>>(src, exv, den, rstart, csr,
                                                         hbuf, F, bias, outT);
}

extern "C" void kernel_launch(void* const* d_in, const int* in_sizes, int n_in,
                              void* d_out, int out_size, void* d_ws, size_t ws_size,
                              hipStream_t stream)
{
    const float* x     = (const float*)d_in[0];
    const int*   src   = (const int*)d_in[1];
    const int*   dst   = (const int*)d_in[2];
    const float* w1    = (const float*)d_in[3];
    const float* b1    = (const float*)d_in[4];
    const float* w2    = (const float*)d_in[5];
    const float* b2    = (const float*)d_in[6];
    const float* w3    = (const float*)d_in[7];
    const float* b3    = (const float*)d_in[8];
    const float* conv1 = (const float*)d_in[9];
    const float* bn1g  = (const float*)d_in[10];
    const float* bn1b  = (const float*)d_in[11];
    const float* g1w   = (const float*)d_in[12];
    const float* g1a   = (const float*)d_in[13];
    const float* g1b   = (const float*)d_in[14];
    const float* conv2 = (const float*)d_in[15];
    const float* bn2g  = (const float*)d_in[16];
    const float* bn2b  = (const float*)d_in[17];
    const float* g2w   = (const float*)d_in[18];
    const float* g2a   = (const float*)d_in[19];
    const float* g2b   = (const float*)d_in[20];
    const float* conv3 = (const float*)d_in[21];
    const float* bn3g  = (const float*)d_in[22];
    const float* bn3b  = (const float*)d_in[23];
    float* out = (float*)d_out;

    char* ws = (char*)d_ws;
    size_t off = 0;
    auto alloc = [&](size_t bytes) -> void* {
        void* p = ws + off;
        off += (bytes + 255) & ~(size_t)255;
        return p;
    };
    float*    h      = (float*)alloc((size_t)N_NODES * 256 * 4); // MLP; later gat1h/gat2h + Xt3
    float*    Xt1    = (float*)alloc((size_t)96  * N_NODES * 4); // dense block 1 (transposed)
    float*    Xt2    = (float*)alloc((size_t)120 * N_NODES * 4); // dense block 2 (transposed)
    float*    exv    = (float*)alloc((size_t)N_EDGES * 4);
    int*      csr    = (int*)alloc((size_t)N_EDGES * 4);
    int*      deg    = (int*)alloc((size_t)N_NODES * 4);
    int*      rtmp   = (int*)alloc((size_t)N_NODES * 4);
    int*      rstart = (int*)alloc((size_t)(N_NODES + 1) * 4);
    int*      cursor = (int*)alloc((size_t)N_NODES * 4);
    int*      parts  = (int*)alloc(2048);
    unsigned* m_u    = (unsigned*)alloc((size_t)N_NODES * 4);
    float*    den    = (float*)alloc((size_t)N_NODES * 4);
    float*    sd     = (float*)alloc((size_t)N_NODES * 4);
    float*    ss     = (float*)alloc((size_t)N_NODES * 4);
    float*    gsum   = (float*)alloc(264 * 4);
    float*    gsq    = gsum + 132;
    float*    ps     = (float*)alloc((size_t)12 * DENSE_GRID * 4);
    float*    pq     = (float*)alloc((size_t)12 * DENSE_GRID * 4);

    float* gat1h = h;                                   // [N,48] = 19.2 MB (h free after MLP)
    float* gat2h = h;                                   // [N,60] = 24 MB
    float* Xt3   = (float*)((char*)h + 33554432);       // [132][N] = 52.8 MB at h+32MB (fits in 102.4)

    // ---- CSR by dst (shared by both GATs) ----
    hipMemsetAsync(deg, 0, (size_t)N_NODES * 4, stream);
    hist_kernel<<<2048, 256, 0, stream>>>(dst, deg);
    scan1<<<NODE_GRID, 256, 0, stream>>>(deg, rtmp, parts);
    scan2<<<1, 512, 0, stream>>>(parts, NODE_GRID, rstart + N_NODES);
    scan3<<<NODE_GRID, 256, 0, stream>>>(rtmp, parts, rstart, cursor);
    scatter_k<<<2048, 256, 0, stream>>>(dst, cursor, csr);

    // ---- MLP ----
    gemm_rows<4, false, false><<<GEMM_GRID, 256, 0, stream>>>(x, w1, b1, h,   64,  256, 256, 0.01f);
    gemm_rows<4, false, false><<<GEMM_GRID, 256, 0, stream>>>(h, w2, b2, h,   256, 256, 256, 0.01f);
    gemm_rows<1, false, true ><<<GEMM_GRID, 256, 0, stream>>>(h, w3, b3, Xt1, 256, 24, N_NODES, 0.01f);

    // ---- dense block 1 (24 -> 96, channel-major) ----
    run_dense_block_t(stream, Xt1, 24, conv1, 84, bn1g, bn1b, gsum, gsq, ps, pq);

    // ---- GAT 1 (96 -> 48), output transposed into Xt2 rows 0..47 ----
    run_gat(stream, Xt1, 96, g1w, g1a, g1b, 48, gat1h, Xt2,
            src, dst, sd, ss, m_u, den, exv, rstart, csr);

    // ---- dense block 2 (48 -> 120) ----
    run_dense_block_t(stream, Xt2, 48, conv2, 108, bn2g, bn2b, gsum, gsq, ps, pq);

    // ---- GAT 2 (120 -> 60), output transposed into Xt3 rows 0..59 ----
    run_gat(stream, Xt2, 120, g2w, g2a, g2b, 60, gat2h, Xt3,
            src, dst, sd, ss, m_u, den, exv, rstart, csr);

    // ---- dense block 3 (60 -> 132) ----
    run_dense_block_t(stream, Xt3, 60, conv3, 120, bn3g, bn3b, gsum, gsq, ps, pq);

    // ---- final transpose to row-major d_out ----
    transpose_out<<<GEMM_GRID, 256, 0, stream>>>(Xt3, out);
}

// Round 5
// 1572.244 us; speedup vs baseline: 3.6755x; 1.1650x over previous
//
#include <hip/hip_runtime.h>
#include <math.h>

#define N_NODES 100000
#define N_EDGES 1600000

static constexpr int GEMM_GRID = (N_NODES + 63) / 64;     // 1563
static constexpr int NODE_GRID = (N_NODES + 255) / 256;   // 391
static constexpr int DENSE_GRID = (N_NODES + 63) / 64;    // 1563
static constexpr unsigned M_INIT = 0x007FFFFFu;           // fmap(-inf)

typedef __attribute__((ext_vector_type(8))) short     bf16x8;
typedef __attribute__((ext_vector_type(8))) unsigned short ushort8_t;
typedef __attribute__((ext_vector_type(4))) float     f32x4;

__device__ __forceinline__ float lrelu(float v, float s){ return v >= 0.f ? v : v*s; }

__device__ __forceinline__ unsigned fmap(float v){
    unsigned u = __float_as_uint(v);
    return (u & 0x80000000u) ? ~u : (u | 0x80000000u);
}

__device__ __forceinline__ unsigned short f2bf(float f){
    unsigned u = __float_as_uint(f);
    unsigned r = (u + 0x7FFFu + ((u >> 16) & 1u)) >> 16;   // RNE
    return (unsigned short)r;
}

// ---------------- weight transpose+convert: wt[n][k] = bf16(w[k][n]) ----------------
__global__ void cvt_wT(const float* __restrict__ w, unsigned short* __restrict__ wt,
                       int K, int Nsrc, int Npad)
{
    int idx = blockIdx.x * 256 + threadIdx.x;
    if (idx >= Npad * K) return;
    int n = idx / K, k = idx % K;
    float v = (n < Nsrc) ? w[(long)k * Nsrc + n] : 0.f;
    wt[idx] = f2bf(v);
}

// ---------------- MFMA MLP layer: Out[bf16 N x 256] = leaky(A @ Wt^T + bias) --------
// A: [N_NODES][KV] (f32 if AF32 else bf16). Wt: [256][KV] bf16 (pre-transposed).
// Block = 256 thr / 4 waves, 64 rows; wave w owns cols w*64..w*64+63.
template<int KV, bool AF32>
__global__ __launch_bounds__(256) void mlp_mfma_256(
    const void* __restrict__ Aptr, const unsigned short* __restrict__ wt,
    const float* __restrict__ bias, unsigned short* __restrict__ Out)
{
    constexpr int AS = KV + 8;                 // LDS row stride (bf16), b128-aligned + spread
    __shared__ unsigned short lds[64 * 264];   // A-stage (64*AS) and out-stage (stride 264)
    const int t = threadIdx.x;
    const int r0 = blockIdx.x * 64;
    const int wv = t >> 6, lane = t & 63;
    const int l15 = lane & 15, grp = lane >> 4;
    const int cw = wv * 64;

    // ---- stage A tile (64 x KV) into LDS as bf16 ----
    constexpr int cpr = KV / 8;                // 8-elem chunks per row
    if (AF32) {
        const float* A = (const float*)Aptr;
        for (int c = t; c < 64 * cpr; c += 256) {
            int row = c / cpr, kc = c % cpr;
            int gr = r0 + row;
            float4 v0 = make_float4(0,0,0,0), v1 = v0;
            if (gr < N_NODES) {
                v0 = *(const float4*)(A + (long)gr * KV + kc * 8);
                v1 = *(const float4*)(A + (long)gr * KV + kc * 8 + 4);
            }
            unsigned short* p = lds + row * AS + kc * 8;
            p[0]=f2bf(v0.x); p[1]=f2bf(v0.y); p[2]=f2bf(v0.z); p[3]=f2bf(v0.w);
            p[4]=f2bf(v1.x); p[5]=f2bf(v1.y); p[6]=f2bf(v1.z); p[7]=f2bf(v1.w);
        }
    } else {
        const unsigned short* A = (const unsigned short*)Aptr;
        for (int c = t; c < 64 * cpr; c += 256) {
            int row = c / cpr, kc = c % cpr;
            int gr = r0 + row;
            ushort8_t v = {0,0,0,0,0,0,0,0};
            if (gr < N_NODES)
                v = *(const ushort8_t*)(A + (long)gr * KV + kc * 8);
            *(ushort8_t*)(lds + row * AS + kc * 8) = v;
        }
    }
    __syncthreads();

    f32x4 acc[4][4];
#pragma unroll
    for (int i = 0; i < 4; i++)
#pragma unroll
        for (int j = 0; j < 4; j++) acc[i][j] = (f32x4){0.f,0.f,0.f,0.f};

#pragma unroll
    for (int ks = 0; ks < KV / 32; ks++) {
        bf16x8 a[4], b[4];
#pragma unroll
        for (int i = 0; i < 4; i++)
            a[i] = *(const bf16x8*)(lds + (i*16 + l15) * AS + ks*32 + grp*8);
#pragma unroll
        for (int j = 0; j < 4; j++)
            b[j] = *(const bf16x8*)(wt + (size_t)(cw + j*16 + l15) * KV + ks*32 + grp*8);
#pragma unroll
        for (int i = 0; i < 4; i++)
#pragma unroll
            for (int j = 0; j < 4; j++)
                acc[i][j] = __builtin_amdgcn_mfma_f32_16x16x32_bf16(a[i], b[j], acc[i][j], 0, 0, 0);
    }

    __syncthreads();   // all LDS A-reads done before out-staging reuses it
#pragma unroll
    for (int i = 0; i < 4; i++)
#pragma unroll
        for (int j = 0; j < 4; j++)
#pragma unroll
            for (int r = 0; r < 4; r++) {
                int rl = i*16 + grp*4 + r;
                int cl = cw + j*16 + l15;
                float v = acc[i][j][r] + bias[cl];
                v = lrelu(v, 0.01f);
                lds[rl * 264 + cl] = f2bf(v);
            }
    __syncthreads();
    for (int c = t; c < 64 * 32; c += 256) {   // 256 cols = 32 chunks of 8
        int row = c >> 5, kc = c & 31;
        int gr = r0 + row;
        if (gr < N_NODES)
            *(ushort8_t*)(Out + (long)gr * 256 + kc * 8) =
                *(const ushort8_t*)(lds + row * 264 + kc * 8);
    }
}

// ---------------- MFMA MLP layer 3: Xt[24][N] = leaky(A @ Wt3^T + bias), TOUT f32 ----
__global__ __launch_bounds__(256) void mlp_mfma_24(
    const unsigned short* __restrict__ A, const unsigned short* __restrict__ wt3,
    const float* __restrict__ bias, float* __restrict__ XtOut)
{
    constexpr int KV = 256, AS = 264;
    __shared__ unsigned short lds[64 * 264];
    const int t = threadIdx.x;
    const int r0 = blockIdx.x * 64;
    const int wv = t >> 6, lane = t & 63;
    const int l15 = lane & 15, grp = lane >> 4;

    constexpr int cpr = KV / 8;
    for (int c = t; c < 64 * cpr; c += 256) {
        int row = c / cpr, kc = c % cpr;
        int gr = r0 + row;
        ushort8_t v = {0,0,0,0,0,0,0,0};
        if (gr < N_NODES)
            v = *(const ushort8_t*)(A + (long)gr * KV + kc * 8);
        *(ushort8_t*)(lds + row * AS + kc * 8) = v;
    }
    __syncthreads();

    f32x4 acc[2] = {(f32x4){0.f,0.f,0.f,0.f}, (f32x4){0.f,0.f,0.f,0.f}};
#pragma unroll
    for (int ks = 0; ks < KV / 32; ks++) {
        bf16x8 a = *(const bf16x8*)(lds + (wv*16 + l15) * AS + ks*32 + grp*8);
#pragma unroll
        for (int j = 0; j < 2; j++) {
            bf16x8 b = *(const bf16x8*)(wt3 + (size_t)(j*16 + l15) * KV + ks*32 + grp*8);
            acc[j] = __builtin_amdgcn_mfma_f32_16x16x32_bf16(a, b, acc[j], 0, 0, 0);
        }
    }

    __syncthreads();
    float* ldsf = (float*)lds;                  // [64][25] f32 out-stage
#pragma unroll
    for (int j = 0; j < 2; j++)
#pragma unroll
        for (int r = 0; r < 4; r++) {
            int cl = j*16 + l15;
            if (cl < 24) {
                int rl = wv*16 + grp*4 + r;
                float v = acc[j][r] + bias[cl];
                ldsf[rl * 25 + cl] = lrelu(v, 0.01f);
            }
        }
    __syncthreads();
    int n = t & 63, c0 = t >> 6;
    int gr = r0 + n;
    if (gr < N_NODES)
        for (int c = c0; c < 24; c += 4)
            XtOut[(long)c * N_NODES + gr] = ldsf[n * 25 + c];
}

// ---------------- generic row-block GEMM (f32, kept for GAT) ----------------
template<int NCT, bool TIN, bool TOUT>
__global__ __launch_bounds__(256) void gemm_rows(
    const float* A, const float* __restrict__ B, const float* __restrict__ bias,
    float* C, int K, int M, int OS, float slope)
{
    constexpr int BNtot = 64 * NCT;
    __shared__ float At[16 * 68];
    __shared__ float Bt[16 * BNtot];
    const int t  = threadIdx.x;
    const int r0 = blockIdx.x * 64;
    const int tx = t & 15, ty = t >> 4;

    float acc[4][4 * NCT];
#pragma unroll
    for (int i = 0; i < 4; i++)
#pragma unroll
        for (int j = 0; j < 4 * NCT; j++) acc[i][j] = 0.f;

    for (int k0 = 0; k0 < K; k0 += 16) {
        if (TIN) {
            int kk = t >> 4, rq = t & 15;
            float4 v = make_float4(0.f, 0.f, 0.f, 0.f);
            if (k0 + kk < K)
                v = *(const float4*)(A + (long)(k0 + kk) * N_NODES + r0 + rq * 4);
            *(float4*)(At + kk * 68 + rq * 4) = v;
        } else {
            int r = t >> 2, kq = t & 3;
            float4 v = make_float4(0.f, 0.f, 0.f, 0.f);
            int row = r0 + r, kk = k0 + kq * 4;
            if (row < N_NODES && kk < K)
                v = *(const float4*)(A + (long)row * K + kk);
            At[(kq*4+0)*68 + r] = v.x;
            At[(kq*4+1)*68 + r] = v.y;
            At[(kq*4+2)*68 + r] = v.z;
            At[(kq*4+3)*68 + r] = v.w;
        }
#pragma unroll
        for (int i = 0; i < NCT; i++) {
            int idx = i * 256 + t;
            constexpr int fpr = BNtot / 4;
            int kk = idx / fpr, mq = idx % fpr;
            float4 v = make_float4(0.f, 0.f, 0.f, 0.f);
            if (k0 + kk < K && mq * 4 < M)
                v = *(const float4*)(B + (long)(k0 + kk) * M + mq * 4);
            *(float4*)(Bt + kk * BNtot + mq * 4) = v;
        }
        __syncthreads();
#pragma unroll
        for (int kk = 0; kk < 16; kk++) {
            float4 av = *(const float4*)(At + kk * 68 + ty * 4);
            float a_[4] = {av.x, av.y, av.z, av.w};
#pragma unroll
            for (int ct = 0; ct < NCT; ct++) {
                float4 bv = *(const float4*)(Bt + kk * BNtot + ct * 64 + tx * 4);
                float b_[4] = {bv.x, bv.y, bv.z, bv.w};
#pragma unroll
                for (int i = 0; i < 4; i++)
#pragma unroll
                    for (int j = 0; j < 4; j++)
                        acc[i][ct*4+j] += a_[i] * b_[j];
            }
        }
        __syncthreads();
    }
#pragma unroll
    for (int i = 0; i < 4; i++) {
        int row = r0 + ty * 4 + i;
        if (row >= N_NODES) continue;
#pragma unroll
        for (int ct = 0; ct < NCT; ct++)
#pragma unroll
            for (int j = 0; j < 4; j++) {
                int col = ct * 64 + tx * 4 + j;
                if (col < M) {
                    float v = acc[i][ct*4+j];
                    if (bias) v += bias[col];
                    v = lrelu(v, slope);
                    if (TOUT) C[(long)col * OS + row] = v;
                    else      C[(long)row * OS + col] = v;
                }
            }
    }
}

// ---------------- BN stats over channel-major layout ----------------
__global__ void bn_stats_t(const float* __restrict__ Xt,
                           float* __restrict__ gsum, float* __restrict__ gsq)
{
    int ch = blockIdx.x, part = blockIdx.y, t = threadIdx.x;
    const float* p = Xt + (long)ch * N_NODES;
    float s = 0.f, q = 0.f;
    for (long i = (long)part * 25000 + t * 4; i < (long)(part + 1) * 25000; i += 1024) {
        float4 v = *(const float4*)(p + i);
        s += v.x + v.y + v.z + v.w;
        q += v.x*v.x + v.y*v.y + v.z*v.z + v.w*v.w;
    }
#pragma unroll
    for (int m = 1; m < 64; m <<= 1) {
        s += __shfl_xor(s, m, 64);
        q += __shfl_xor(q, m, 64);
    }
    __shared__ float ls[4], lq[4];
    int wid = t >> 6;
    if ((t & 63) == 0) { ls[wid] = s; lq[wid] = q; }
    __syncthreads();
    if (t == 0) {
        atomicAdd(gsum + ch, ls[0] + ls[1] + ls[2] + ls[3]);
        atomicAdd(gsq  + ch, lq[0] + lq[1] + lq[2] + lq[3]);
    }
}

// ---------------- reduce per-block partial stats ----------------
__global__ __launch_bounds__(256) void bn_reduce(
    const float* __restrict__ ps, const float* __restrict__ pq,
    float* __restrict__ gsum, float* __restrict__ gsq, int C)
{
    int g = blockIdx.x;
    int t = threadIdx.x;
    float s = 0.f, q = 0.f;
    for (int b = t; b < DENSE_GRID; b += 256) {
        s += ps[g * DENSE_GRID + b];
        q += pq[g * DENSE_GRID + b];
    }
    __shared__ float ls[256], lq[256];
    ls[t] = s; lq[t] = q; __syncthreads();
    for (int o = 128; o > 0; o >>= 1) {
        if (t < o) { ls[t] += ls[t + o]; lq[t] += lq[t + o]; }
        __syncthreads();
    }
    if (t == 0) { gsum[C + g] = ls[0]; gsq[C + g] = lq[0]; }
}

// ---------------- densenet layer, channel-major, no hot atomics ----------------
__global__ __launch_bounds__(64) void dense_conv_t(
    float* __restrict__ Xt, int C,
    const float* __restrict__ W, int WS,
    const float* __restrict__ gamma, const float* __restrict__ beta,
    const float* __restrict__ gsum, const float* __restrict__ gsq,
    float* __restrict__ ps, float* __restrict__ pq)
{
    __shared__ float w_lds[12 * 132];
    __shared__ float a_lds[132], b_lds[132];
    int t = threadIdx.x;
    for (int c = t; c < C; c += 64) {
        float mu  = gsum[c] * (1.f / N_NODES);
        float var = gsq[c]  * (1.f / N_NODES) - mu * mu;
        float A = rsqrtf(var + 1e-5f) * gamma[c];
        a_lds[c] = A;
        b_lds[c] = beta[c] - mu * A;
    }
#pragma unroll
    for (int g = 0; g < 12; g++)
        for (int c = t; c < C; c += 64)
            w_lds[g * 132 + c] = W[g * WS + c];
    __syncthreads();

    long n = (long)blockIdx.x * 64 + t;
    bool valid = (n < N_NODES);
    long nn = valid ? n : (N_NODES - 1);
    const float* xp = Xt + nn;
    float acc[12];
#pragma unroll
    for (int g = 0; g < 12; g++) acc[g] = 0.f;

    float v[12], vn[12];
#pragma unroll
    for (int j = 0; j < 12; j++) v[j] = xp[(long)j * N_NODES];
    for (int c0 = 0; c0 < C; c0 += 12) {
        if (c0 + 12 < C) {
#pragma unroll
            for (int j = 0; j < 12; j++)
                vn[j] = xp[(long)(c0 + 12 + j) * N_NODES];
        }
#pragma unroll
        for (int j = 0; j < 12; j++) {
            int ch = c0 + j;
            float u = a_lds[ch] * v[j] + b_lds[ch];
            u = (u >= 0.f) ? u : 0.01f * u;
#pragma unroll
            for (int g = 0; g < 12; g++)
                acc[g] += u * w_lds[g * 132 + ch];
        }
#pragma unroll
        for (int j = 0; j < 12; j++) v[j] = vn[j];
    }
    if (valid) {
#pragma unroll
        for (int g = 0; g < 12; g++)
            Xt[(long)(C + g) * N_NODES + n] = acc[g];
    }
    float sv[12], qv[12];
#pragma unroll
    for (int g = 0; g < 12; g++) { float v2 = valid ? acc[g] : 0.f; sv[g] = v2; qv[g] = v2 * v2; }
#pragma unroll
    for (int m = 1; m < 64; m <<= 1)
#pragma unroll
        for (int g = 0; g < 12; g++) {
            sv[g] += __shfl_xor(sv[g], m, 64);
            qv[g] += __shfl_xor(qv[g], m, 64);
        }
    if (t == 0) {
        int b = blockIdx.x;
#pragma unroll
        for (int g = 0; g < 12; g++) {
            ps[g * DENSE_GRID + b] = sv[g];
            pq[g * DENSE_GRID + b] = qv[g];
        }
    }
}

// ---------------- GAT ----------------
__global__ void gat_scores(const float* __restrict__ H, int F, const float* __restrict__ a,
                           float* __restrict__ sd, float* __restrict__ ss)
{
    long n = (long)blockIdx.x * 256 + threadIdx.x;
    if (n >= N_NODES) return;
    const float* h = H + n * F;
    float s1 = 0.f, s2 = 0.f;
    for (int f = 0; f < F; f += 4) {
        float4 hv = *(const float4*)(h + f);
        s1 += hv.x*a[f] + hv.y*a[f+1] + hv.z*a[f+2] + hv.w*a[f+3];
        s2 += hv.x*a[F+f] + hv.y*a[F+f+1] + hv.z*a[F+f+2] + hv.w*a[F+f+3];
    }
    sd[n] = s1; ss[n] = s2;
}

__global__ void gat_init(unsigned* __restrict__ m_u, float* __restrict__ den)
{
    long n = (long)blockIdx.x * 256 + threadIdx.x;
    if (n >= N_NODES) return;
    m_u[n] = M_INIT;
    den[n] = 0.f;
}

__global__ void gat_edge1(const int* __restrict__ src, const int* __restrict__ dst,
                          const float* __restrict__ sd, const float* __restrict__ ss,
                          unsigned* __restrict__ m_u)
{
    for (long e = (long)blockIdx.x * 256 + threadIdx.x; e < N_EDGES; e += (long)gridDim.x * 256) {
        int d = dst[e], s = src[e];
        float v = sd[d] + ss[s];
        v = (v >= 0.f) ? v : 0.2f * v;
        atomicMax(m_u + d, fmap(v));
    }
}

__global__ void gat_fixm(unsigned* __restrict__ m_u)
{
    long n = (long)blockIdx.x * 256 + threadIdx.x;
    if (n >= N_NODES) return;
    unsigned u = m_u[n];
    float m;
    if (u == M_INIT) m = 0.f;
    else m = (u & 0x80000000u) ? __uint_as_float(u ^ 0x80000000u) : __uint_as_float(~u);
    m_u[n] = __float_as_uint(m);
}

__global__ void gat_edge2(const int* __restrict__ src, const int* __restrict__ dst,
                          const float* __restrict__ sd, const float* __restrict__ ss,
                          const float* __restrict__ mf, float* __restrict__ exv,
                          float* __restrict__ den)
{
    for (long e = (long)blockIdx.x * 256 + threadIdx.x; e < N_EDGES; e += (long)gridDim.x * 256) {
        int d = dst[e], s = src[e];
        float v = sd[d] + ss[s];
        v = (v >= 0.f) ? v : 0.2f * v;
        float x = __expf(v - mf[d]);
        exv[e] = x;
        atomicAdd(den + d, x);
    }
}

__global__ __launch_bounds__(256) void gat_aggregate(
    const int* __restrict__ src, const float* __restrict__ exv,
    const float* __restrict__ den, const int* __restrict__ rstart,
    const int* __restrict__ csr, const float* __restrict__ H, int F,
    const float* __restrict__ bias, float* __restrict__ outT)
{
    int wid  = threadIdx.x >> 6;
    int lane = threadIdx.x & 63;
    long node = (long)blockIdx.x * 4 + wid;
    if (node >= N_NODES) return;
    int st = rstart[node], en = rstart[node + 1];
    float invden = 1.f / (den[node] + 1e-16f);
    float acc = 0.f;
    for (int base = st; base < en; base += 64) {
        int cnt = min(64, en - base);
        float al = 0.f; int sj = 0;
        if (lane < cnt) {
            int eid = csr[base + lane];
            al = exv[eid] * invden;
            sj = src[eid];
        }
        for (int j = 0; j < cnt; j++) {
            float a = __shfl(al, j, 64);
            int   s = __shfl(sj, j, 64);
            if (lane < F) acc += a * H[(long)s * F + lane];
        }
    }
    if (lane < F) outT[(long)lane * N_NODES + node] = acc + bias[lane];
}

// ---------------- final transpose [132][N] -> [N,132] ----------------
__global__ __launch_bounds__(256) void transpose_out(const float* __restrict__ Xt,
                                                     float* __restrict__ out)
{
    __shared__ float tile[64 * 133];
    int t = threadIdx.x;
    long n0 = (long)blockIdx.x * 64;
    int lane = t & 63, cq = t >> 6;
    for (int c = cq; c < 132; c += 4) {
        long n = n0 + lane;
        float v = (n < N_NODES) ? Xt[(long)c * N_NODES + n] : 0.f;
        tile[lane * 133 + c] = v;
    }
    __syncthreads();
    for (int idx = t; idx < 64 * 132; idx += 256) {
        int r = idx / 132, c = idx % 132;
        long n = n0 + r;
        if (n < N_NODES) out[n * 132 + c] = tile[r * 133 + c];
    }
}

// ---------------- CSR build ----------------
__global__ void hist_kernel(const int* __restrict__ dst, int* __restrict__ deg)
{
    for (long e = (long)blockIdx.x * 256 + threadIdx.x; e < N_EDGES; e += (long)gridDim.x * 256)
        atomicAdd(deg + dst[e], 1);
}

__global__ void scan1(const int* __restrict__ deg, int* __restrict__ rtmp, int* __restrict__ parts)
{
    __shared__ int ls[256];
    int t = threadIdx.x;
    long i = (long)blockIdx.x * 256 + t;
    int v = (i < N_NODES) ? deg[i] : 0;
    ls[t] = v; __syncthreads();
    for (int o = 1; o < 256; o <<= 1) {
        int y = (t >= o) ? ls[t - o] : 0;
        __syncthreads();
        ls[t] += y;
        __syncthreads();
    }
    if (i < N_NODES) rtmp[i] = ls[t] - v;
    if (t == 255) parts[blockIdx.x] = ls[255];
}

__global__ void scan2(int* __restrict__ parts, int nb, int* __restrict__ total_out)
{
    __shared__ int ls[512];
    int t = threadIdx.x;
    int v = (t < nb) ? parts[t] : 0;
    ls[t] = v; __syncthreads();
    for (int o = 1; o < 512; o <<= 1) {
        int y = (t >= o) ? ls[t - o] : 0;
        __syncthreads();
        ls[t] += y;
        __syncthreads();
    }
    if (t < nb) parts[t] = ls[t] - v;
    if (t == 0) total_out[0] = ls[511];
}

__global__ void scan3(const int* __restrict__ rtmp, const int* __restrict__ parts,
                      int* __restrict__ rstart, int* __restrict__ cursor)
{
    long i = (long)blockIdx.x * 256 + threadIdx.x;
    if (i < N_NODES) {
        int v = rtmp[i] + parts[i >> 8];
        rstart[i] = v;
        cursor[i] = v;
    }
}

__global__ void scatter_k(const int* __restrict__ dst, int* __restrict__ cursor,
                          int* __restrict__ csr)
{
    for (long e = (long)blockIdx.x * 256 + threadIdx.x; e < N_EDGES; e += (long)gridDim.x * 256) {
        int pos = atomicAdd(cursor + dst[e], 1);
        csr[pos] = (int)e;
    }
}

// ---------------- host helpers ----------------
static void run_dense_block_t(hipStream_t stream, float* Xt, int C0,
                              const float* convW, int WS,
                              const float* gamma, const float* beta,
                              float* gsum, float* gsq, float* ps, float* pq)
{
    hipMemsetAsync(gsum, 0, 264 * sizeof(float), stream);
    bn_stats_t<<<dim3(C0, 4), 256, 0, stream>>>(Xt, gsum, gsq);
    for (int i = 0; i < 6; i++) {
        int C = C0 + 12 * i;
        dense_conv_t<<<DENSE_GRID, 64, 0, stream>>>(Xt, C, convW + (size_t)i * 12 * WS, WS,
                                                    gamma + (size_t)i * WS, beta + (size_t)i * WS,
                                                    gsum, gsq, ps, pq);
        if (i < 5)
            bn_reduce<<<12, 256, 0, stream>>>(ps, pq, gsum, gsq, C);
    }
}

static void run_gat(hipStream_t stream, const float* XtIn, int K,
                    const float* W, const float* a, const float* bias, int F,
                    float* hbuf, float* outT,
                    const int* src, const int* dst,
                    float* sd, float* ss, unsigned* m_u, float* den,
                    float* exv, const int* rstart, const int* csr)
{
    gemm_rows<1, true, false><<<GEMM_GRID, 256, 0, stream>>>(XtIn, W, nullptr, hbuf, K, F, F, 1.0f);
    gat_scores<<<NODE_GRID, 256, 0, stream>>>(hbuf, F, a, sd, ss);
    gat_init<<<NODE_GRID, 256, 0, stream>>>(m_u, den);
    gat_edge1<<<2048, 256, 0, stream>>>(src, dst, sd, ss, m_u);
    gat_fixm<<<NODE_GRID, 256, 0, stream>>>(m_u);
    gat_edge2<<<2048, 256, 0, stream>>>(src, dst, sd, ss, (const float*)m_u, exv, den);
    gat_aggregate<<<(N_NODES + 3) / 4, 256, 0, stream>>>(src, exv, den, rstart, csr,
                                                         hbuf, F, bias, outT);
}

extern "C" void kernel_launch(void* const* d_in, const int* in_sizes, int n_in,
                              void* d_out, int out_size, void* d_ws, size_t ws_size,
                              hipStream_t stream)
{
    const float* x     = (const float*)d_in[0];
    const int*   src   = (const int*)d_in[1];
    const int*   dst   = (const int*)d_in[2];
    const float* w1    = (const float*)d_in[3];
    const float* b1    = (const float*)d_in[4];
    const float* w2    = (const float*)d_in[5];
    const float* b2    = (const float*)d_in[6];
    const float* w3    = (const float*)d_in[7];
    const float* b3    = (const float*)d_in[8];
    const float* conv1 = (const float*)d_in[9];
    const float* bn1g  = (const float*)d_in[10];
    const float* bn1b  = (const float*)d_in[11];
    const float* g1w   = (const float*)d_in[12];
    const float* g1a   = (const float*)d_in[13];
    const float* g1b   = (const float*)d_in[14];
    const float* conv2 = (const float*)d_in[15];
    const float* bn2g  = (const float*)d_in[16];
    const float* bn2b  = (const float*)d_in[17];
    const float* g2w   = (const float*)d_in[18];
    const float* g2a   = (const float*)d_in[19];
    const float* g2b   = (const float*)d_in[20];
    const float* conv3 = (const float*)d_in[21];
    const float* bn3g  = (const float*)d_in[22];
    const float* bn3b  = (const float*)d_in[23];
    float* out = (float*)d_out;

    char* ws = (char*)d_ws;
    size_t off = 0;
    auto alloc = [&](size_t bytes) -> void* {
        void* p = ws + off;
        off += (bytes + 255) & ~(size_t)255;
        return p;
    };
    unsigned short* hb1 = (unsigned short*)alloc((size_t)N_NODES * 256 * 2); // 51.2 MB
    unsigned short* hb2 = (unsigned short*)alloc((size_t)N_NODES * 256 * 2); // 51.2 MB
    float*    Xt1    = (float*)alloc((size_t)96  * N_NODES * 4);
    float*    Xt2    = (float*)alloc((size_t)120 * N_NODES * 4);
    float*    exv    = (float*)alloc((size_t)N_EDGES * 4);
    int*      csr    = (int*)alloc((size_t)N_EDGES * 4);
    int*      deg    = (int*)alloc((size_t)N_NODES * 4);
    int*      rtmp   = (int*)alloc((size_t)N_NODES * 4);
    int*      rstart = (int*)alloc((size_t)(N_NODES + 1) * 4);
    int*      cursor = (int*)alloc((size_t)N_NODES * 4);
    int*      parts  = (int*)alloc(2048);
    unsigned* m_u    = (unsigned*)alloc((size_t)N_NODES * 4);
    float*    den    = (float*)alloc((size_t)N_NODES * 4);
    float*    sd     = (float*)alloc((size_t)N_NODES * 4);
    float*    ss     = (float*)alloc((size_t)N_NODES * 4);
    float*    gsum   = (float*)alloc(264 * 4);
    float*    gsq    = gsum + 132;
    float*    ps     = (float*)alloc((size_t)12 * DENSE_GRID * 4);
    float*    pq     = (float*)alloc((size_t)12 * DENSE_GRID * 4);
    unsigned short* wt1 = (unsigned short*)alloc(256 * 64 * 2);
    unsigned short* wt2 = (unsigned short*)alloc(256 * 256 * 2);
    unsigned short* wt3 = (unsigned short*)alloc(32 * 256 * 2);

    // hb1+hb2 = 102.4 MB contiguous; reused after the MLP:
    float* gat1h = (float*)hb1;                          // [N,48] f32 = 19.2 MB
    float* gat2h = (float*)hb1;                          // [N,60] f32 = 24 MB
    float* Xt3   = (float*)((char*)hb1 + 33554432);      // [132][N] f32 = 52.8 MB

    // ---- CSR by dst (shared by both GATs) ----
    hipMemsetAsync(deg, 0, (size_t)N_NODES * 4, stream);
    hist_kernel<<<2048, 256, 0, stream>>>(dst, deg);
    scan1<<<NODE_GRID, 256, 0, stream>>>(deg, rtmp, parts);
    scan2<<<1, 512, 0, stream>>>(parts, NODE_GRID, rstart + N_NODES);
    scan3<<<NODE_GRID, 256, 0, stream>>>(rtmp, parts, rstart, cursor);
    scatter_k<<<2048, 256, 0, stream>>>(dst, cursor, csr);

    // ---- weight prep (f32 -> transposed bf16) ----
    cvt_wT<<<(256 * 64  + 255) / 256, 256, 0, stream>>>(w1, wt1, 64,  256, 256);
    cvt_wT<<<(256 * 256 + 255) / 256, 256, 0, stream>>>(w2, wt2, 256, 256, 256);
    cvt_wT<<<(32  * 256 + 255) / 256, 256, 0, stream>>>(w3, wt3, 256, 24,  32);

    // ---- MLP (bf16 MFMA) ----
    mlp_mfma_256<64,  true ><<<GEMM_GRID, 256, 0, stream>>>(x,   wt1, b1, hb1);
    mlp_mfma_256<256, false><<<GEMM_GRID, 256, 0, stream>>>(hb1, wt2, b2, hb2);
    mlp_mfma_24<<<GEMM_GRID, 256, 0, stream>>>(hb2, wt3, b3, Xt1);

    // ---- dense block 1 (24 -> 96, channel-major) ----
    run_dense_block_t(stream, Xt1, 24, conv1, 84, bn1g, bn1b, gsum, gsq, ps, pq);

    // ---- GAT 1 (96 -> 48), output transposed into Xt2 rows 0..47 ----
    run_gat(stream, Xt1, 96, g1w, g1a, g1b, 48, gat1h, Xt2,
            src, dst, sd, ss, m_u, den, exv, rstart, csr);

    // ---- dense block 2 (48 -> 120) ----
    run_dense_block_t(stream, Xt2, 48, conv2, 108, bn2g, bn2b, gsum, gsq, ps, pq);

    // ---- GAT 2 (120 -> 60), output transposed into Xt3 rows 0..59 ----
    run_gat(stream, Xt2, 120, g2w, g2a, g2b, 60, gat2h, Xt3,
            src, dst, sd, ss, m_u, den, exv, rstart, csr);

    // ---- dense block 3 (60 -> 132) ----
    run_dense_block_t(stream, Xt3, 60, conv3, 120, bn3g, bn3b, gsum, gsq, ps, pq);

    // ---- final transpose to row-major d_out ----
    transpose_out<<<GEMM_GRID, 256, 0, stream>>>(Xt3, out);
}